// Round 17
// baseline (70.245 us; speedup 1.0000x reference)
//
#include <hip/hip_runtime.h>

// 5-layer MLP [B,64]->32->12->8->6->2, fp32 in/out.
// Layer 0 on matrix cores, TRANSPOSED (D' = W0^T x x^T) via
// v_mfma_f32_32x32x16_bf16, 3-pass truncated-bf16 split; feature halves
// aligned with v_permlane32_swap_b32 (R15-proven, no LDS transpose).
// R17: prefetch DISTANCE-3 ring of four 4KB chunk buffers. Prologue stages
// chunks 0..2; each phase stages chunk c+3 then waits vmcnt(12) (= drain
// only the oldest STAGE of the 3+1 in flight). Every chunk has >=3 phases
// + one tail (>2000 cy) of slack before consumption -> vmcnt stalls gone.
// Staging = R6-swizzled global_load_lds (proven); wave-private LDS, no
// __syncthreads. Tail layers scalar fmaf (s_load weights).

typedef __attribute__((ext_vector_type(8))) short short8;
typedef __attribute__((ext_vector_type(16))) float f32x16;
typedef __attribute__((ext_vector_type(4))) unsigned uint4v;
typedef __attribute__((address_space(3))) void* as3p;
typedef const __attribute__((address_space(1))) void* as1p;

#define BLOCK 64
#define NT 4   // 64-row tiles per wave; 4 chunk-phases per tile

__device__ __forceinline__ unsigned fbits(float x) {
    return __builtin_bit_cast(unsigned, x);
}
__device__ __forceinline__ float asf(unsigned u) {
    return __builtin_bit_cast(float, u);
}
// (hi16(ub)<<16) | hi16(ua)  -- one v_perm_b32
__device__ __forceinline__ unsigned packhi(unsigned ua, unsigned ub) {
    return __builtin_amdgcn_perm(ub, ua, 0x07060302u);
}
// 8 floats -> 8 truncated bf16 (element j = k-index j)
__device__ __forceinline__ short8 mk_hi(const float* f) {
    uint4v w;
#pragma unroll
    for (int t = 0; t < 4; ++t)
        w[t] = packhi(fbits(f[2 * t]), fbits(f[2 * t + 1]));
    return __builtin_bit_cast(short8, w);
}
// 8 floats -> bf16 of the truncation residuals
__device__ __forceinline__ short8 mk_lo(const float* f) {
    uint4v w;
#pragma unroll
    for (int t = 0; t < 4; ++t) {
        const float la = f[2 * t]     - asf(fbits(f[2 * t])     & 0xFFFF0000u);
        const float lb = f[2 * t + 1] - asf(fbits(f[2 * t + 1]) & 0xFFFF0000u);
        w[t] = packhi(fbits(la), fbits(lb));
    }
    return __builtin_bit_cast(short8, w);
}
#define MFMA(A, B, C) __builtin_amdgcn_mfma_f32_32x32x16_bf16(A, B, C, 0, 0, 0)

template <int IN, int OUT, bool RELU>
__device__ __forceinline__ void layer(const float* __restrict__ W,
                                      const float* __restrict__ b,
                                      const float* h_in, float* h_out) {
#pragma unroll
    for (int o = 0; o < OUT; ++o) h_out[o] = b[o];
#pragma unroll
    for (int i = 0; i < IN; ++i) {
        const float v = h_in[i];
#pragma unroll
        for (int o = 0; o < OUT; ++o)
            h_out[o] = fmaf(v, W[i * OUT + o], h_out[o]);   // uniform -> s_load
    }
    if (RELU) {
#pragma unroll
        for (int o = 0; o < OUT; ++o) h_out[o] = fmaxf(h_out[o], 0.0f);
    }
}

__global__ __launch_bounds__(BLOCK, 4) void mlp_kernel(
        const float* __restrict__ x,
        const float* __restrict__ W0, const float* __restrict__ b0,
        const float* __restrict__ W1, const float* __restrict__ b1,
        const float* __restrict__ W2, const float* __restrict__ b2,
        const float* __restrict__ W3, const float* __restrict__ b3,
        const float* __restrict__ W4, const float* __restrict__ b4,
        float* __restrict__ out, int nrows) {
    extern __shared__ char lds[];
    char* const qb0 = lds;             // ring of 4 x 4KB chunk buffers
    char* const qb1 = lds + 4096;
    char* const qb2 = lds + 8192;
    char* const qb3 = lds + 12288;

    const int lane = threadIdx.x;          // 1 wave per block
    const long long row0 = (long long)blockIdx.x * (NT * 64);
    const char* xbase = reinterpret_cast<const char*>(x + row0 * 64);

    // --- R6/R10-proven per-lane staging source offset (inverse swizzle).
    const int hh = lane >> 3;
    const int qq = (lane & 7) ^ hh;
    const int stage_off = (2 * hh + (qq >> 2)) * 256 + (qq & 3) * 16;

    // --- x-fragment LDS read offsets (B operand): lane holds
    //     x[row = lane&31][k = 16c + 8*hA + j] (and row+32 for accB).
    const int r0 = lane & 31;
    const int hA = lane >> 5;
    auto lds_off = [](int r, int u) {
        const int R = r >> 1, p = r & 1;
        return R * 128 + (((u + 4 * p) ^ (R & 7)) << 4);
    };
    const int aoff0 = lds_off(r0, 2 * hA);
    const int aoff1 = lds_off(r0, 2 * hA + 1);
    const int aoff2 = lds_off(r0 + 32, 2 * hA);
    const int aoff3 = lds_off(r0 + 32, 2 * hA + 1);

    // --- W0^T fragments (A operand), built once, held in registers.
    //     k-step s: A[o = lane&31][k = 16s + 8*hA + j] = W0[k][o].
    const int colB = lane & 31;
    short8 W0h_, W0l_, W1h_, W1l_, W2h_, W2l_, W3h_, W3l_;
    {
        float wf[8];
#define LOADB(s, BH, BL)                                                \
        {                                                               \
            _Pragma("unroll")                                           \
            for (int j = 0; j < 8; ++j)                                 \
                wf[j] = W0[((s) * 16 + 8 * hA + j) * 32 + colB];        \
            BH = mk_hi(wf);                                             \
            BL = mk_lo(wf);                                             \
        }
        LOADB(0, W0h_, W0l_)
        LOADB(1, W1h_, W1l_)
        LOADB(2, W2h_, W2l_)
        LOADB(3, W3h_, W3l_)
#undef LOADB
    }

    // Stage global chunk gc (tile gc>>2, col-chunk gc&3) into buf.
    auto STAGE = [&](int gc, char* buf) {
        const char* s0 = xbase + (gc >> 2) * (64 * 256) + (gc & 3) * 64 +
                         stage_off;
#pragma unroll
        for (int k = 0; k < 4; ++k)
            __builtin_amdgcn_global_load_lds((as1p)(s0 + k * 4096),
                                             (as3p)(buf + k * 1024), 16, 0, 0);
    };

    // Prologue: stage chunks 0..2 (12 loads in flight).
    STAGE(0, qb0);
    STAGE(1, qb1);
    STAGE(2, qb2);

#pragma unroll 1
    for (int tt = 0; tt < NT; ++tt) {
        f32x16 accA, accB;   // D'[o][r]: cols r = batch rows (accA: 0-31)
#pragma unroll
        for (int r = 0; r < 16; ++r) { accA[r] = 0.0f; accB[r] = 0.0f; }

#define CHUNK_BODY(CUR, WH, WL)                                            \
        {                                                                  \
            float fA[8], fB[8];                                            \
            const float4 q0 = *reinterpret_cast<const float4*>(CUR + aoff0); \
            const float4 q1 = *reinterpret_cast<const float4*>(CUR + aoff1); \
            const float4 q2 = *reinterpret_cast<const float4*>(CUR + aoff2); \
            const float4 q3 = *reinterpret_cast<const float4*>(CUR + aoff3); \
            fA[0]=q0.x; fA[1]=q0.y; fA[2]=q0.z; fA[3]=q0.w;                \
            fA[4]=q1.x; fA[5]=q1.y; fA[6]=q1.z; fA[7]=q1.w;                \
            fB[0]=q2.x; fB[1]=q2.y; fB[2]=q2.z; fB[3]=q2.w;                \
            fB[4]=q3.x; fB[5]=q3.y; fB[6]=q3.z; fB[7]=q3.w;                \
            const short8 Xh = mk_hi(fA), Xl = mk_lo(fA);                   \
            const short8 Yh = mk_hi(fB), Yl = mk_lo(fB);                   \
            accA = MFMA(WH, Xh, accA);                                     \
            accA = MFMA(WL, Xh, accA);                                     \
            accA = MFMA(WH, Xl, accA);                                     \
            accB = MFMA(WH, Yh, accB);                                     \
            accB = MFMA(WL, Yh, accB);                                     \
            accB = MFMA(WH, Yl, accB);                                     \
        }
// Ring phase: consume chunk gc from buffer c&3; stage chunk gc+3 into
// buffer (c+3)&3 (same buffer that held chunk gc-1, consumed last phase:
// WAR distance identical to the proven R15 depth-1 structure).
#define PHASE(c, WH, WL)                                                   \
        {                                                                  \
            const int gc = tt * 4 + (c);                                   \
            char* cur = ((c) & 3) == 0 ? qb0 : ((c) & 3) == 1 ? qb1        \
                       : ((c) & 3) == 2 ? qb2 : qb3;                       \
            char* nxt = (((c) + 3) & 3) == 0 ? qb0                         \
                       : (((c) + 3) & 3) == 1 ? qb1                        \
                       : (((c) + 3) & 3) == 2 ? qb2 : qb3;                 \
            if (gc + 3 < NT * 4) {                                         \
                STAGE(gc + 3, nxt);                                        \
                asm volatile("s_waitcnt vmcnt(12)" ::: "memory");          \
            } else if (gc == NT * 4 - 3) {                                 \
                asm volatile("s_waitcnt vmcnt(8)" ::: "memory");           \
            } else if (gc == NT * 4 - 2) {                                 \
                asm volatile("s_waitcnt vmcnt(4)" ::: "memory");           \
            } else {                                                       \
                asm volatile("s_waitcnt vmcnt(0)" ::: "memory");           \
            }                                                              \
            __builtin_amdgcn_sched_barrier(0);                             \
            CHUNK_BODY(cur, WH, WL)                                        \
        }

        PHASE(0, W0h_, W0l_)
        PHASE(1, W1h_, W1l_)
        PHASE(2, W2h_, W2l_)
        PHASE(3, W3h_, W3l_)
#undef PHASE
#undef CHUNK_BODY

        // --- Align feature halves with permlane32_swap; bias+ReLU in-reg.
        float xr[32];
#pragma unroll
        for (int reg = 0; reg < 16; ++reg) {
            float a = accA[reg];
            float b = accB[reg];
            asm("v_permlane32_swap_b32 %0, %1" : "+v"(a), "+v"(b));
            const int f0 = (reg & 3) + 8 * (reg >> 2);
            xr[f0]     = fmaxf(a + b0[f0],     0.0f);
            xr[f0 + 4] = fmaxf(b + b0[f0 + 4], 0.0f);
        }

        // Tail layers (3 chunk-STAGEs of the next tile fly during these).
        float h1[12], h2[8], h3[6], h4[2];
        layer<32, 12, true>(W1, b1, xr, h1);
        layer<12, 8, true>(W2, b2, h1, h2);
        layer<8, 6, true>(W3, b3, h2, h3);
        layer<6, 2, false>(W4, b4, h3, h4);

        reinterpret_cast<float2*>(out)[row0 + tt * 64 + lane] =
            make_float2(h4[0], h4[1]);
    }
}

extern "C" void kernel_launch(void* const* d_in, const int* in_sizes, int n_in,
                              void* d_out, int out_size, void* d_ws, size_t ws_size,
                              hipStream_t stream) {
    const float* x  = (const float*)d_in[0];
    const float* W0 = (const float*)d_in[1];
    const float* b0 = (const float*)d_in[2];
    const float* W1 = (const float*)d_in[3];
    const float* b1 = (const float*)d_in[4];
    const float* W2 = (const float*)d_in[5];
    const float* b2 = (const float*)d_in[6];
    const float* W3 = (const float*)d_in[7];
    const float* b3 = (const float*)d_in[8];
    const float* W4 = (const float*)d_in[9];
    const float* b4 = (const float*)d_in[10];
    float* out = (float*)d_out;

    const int nrows = in_sizes[0] / 64;                 // 1,048,576
    const int rows_per_block = NT * 64;                 // 256
    const int grid = nrows / rows_per_block;            // 4096 (exact)
    const size_t shmem = 16384;                         // 4 x 4KB ring

    mlp_kernel<<<grid, BLOCK, shmem, stream>>>(x, W0, b0, W1, b1, W2, b2,
                                               W3, b3, W4, b4, out, nrows);
}

// Round 18
// 66.465 us; speedup vs baseline: 1.0569x; 1.0569x over previous
//
#include <hip/hip_runtime.h>

// 5-layer MLP [B,64]->32->12->8->6->2, fp32 in/out.
// Layer 0 on matrix cores, TRANSPOSED (D' = W0^T x x^T) via
// v_mfma_f32_32x32x16_bf16, 3-pass truncated-bf16 split; feature halves
// aligned with v_permlane32_swap_b32 (R15-proven epilogue, verbatim).
// R18: DENSE DMA sourcing. Half-tile = 32 rows x 256B staged with 8
// contiguous-1KB global_load_lds calls (lane*16 -> 8 full 128B lines per
// instr, the m13-optimal HBM pattern). Conflict fix moved to the LDS DEST:
// call k's base = k*1072 (48B pad per 4-row group) -> row r at
// r*256 + (r>>2)*48 -> ds_read_b128 at the 8-lane/quad floor (3G mod 8
// bijection). accA <- buffer0 (rows 0-31), accB <- buffer1 (rows 32-63),
// double-buffered, counted vmcnt(8), wave-private LDS, no __syncthreads.

typedef __attribute__((ext_vector_type(8))) short short8;
typedef __attribute__((ext_vector_type(16))) float f32x16;
typedef __attribute__((ext_vector_type(4))) unsigned uint4v;
typedef __attribute__((address_space(3))) void* as3p;
typedef const __attribute__((address_space(1))) void* as1p;

#define BLOCK 64
#define NT 4                 // 64-row tiles per wave; 2 half-tile phases each
#define BUFSZ 8576           // 32*256 + 8*48 pad

__device__ __forceinline__ unsigned fbits(float x) {
    return __builtin_bit_cast(unsigned, x);
}
__device__ __forceinline__ float asf(unsigned u) {
    return __builtin_bit_cast(float, u);
}
// (hi16(ub)<<16) | hi16(ua)  -- one v_perm_b32
__device__ __forceinline__ unsigned packhi(unsigned ua, unsigned ub) {
    return __builtin_amdgcn_perm(ub, ua, 0x07060302u);
}
// 8 floats -> 8 truncated bf16 (element j = k-index j)
__device__ __forceinline__ short8 mk_hi(const float* f) {
    uint4v w;
#pragma unroll
    for (int t = 0; t < 4; ++t)
        w[t] = packhi(fbits(f[2 * t]), fbits(f[2 * t + 1]));
    return __builtin_bit_cast(short8, w);
}
// 8 floats -> bf16 of the truncation residuals
__device__ __forceinline__ short8 mk_lo(const float* f) {
    uint4v w;
#pragma unroll
    for (int t = 0; t < 4; ++t) {
        const float la = f[2 * t]     - asf(fbits(f[2 * t])     & 0xFFFF0000u);
        const float lb = f[2 * t + 1] - asf(fbits(f[2 * t + 1]) & 0xFFFF0000u);
        w[t] = packhi(fbits(la), fbits(lb));
    }
    return __builtin_bit_cast(short8, w);
}
#define MFMA(A, B, C) __builtin_amdgcn_mfma_f32_32x32x16_bf16(A, B, C, 0, 0, 0)

template <int IN, int OUT, bool RELU>
__device__ __forceinline__ void layer(const float* __restrict__ W,
                                      const float* __restrict__ b,
                                      const float* h_in, float* h_out) {
#pragma unroll
    for (int o = 0; o < OUT; ++o) h_out[o] = b[o];
#pragma unroll
    for (int i = 0; i < IN; ++i) {
        const float v = h_in[i];
#pragma unroll
        for (int o = 0; o < OUT; ++o)
            h_out[o] = fmaf(v, W[i * OUT + o], h_out[o]);   // uniform -> s_load
    }
    if (RELU) {
#pragma unroll
        for (int o = 0; o < OUT; ++o) h_out[o] = fmaxf(h_out[o], 0.0f);
    }
}

__global__ __launch_bounds__(BLOCK, 3) void mlp_kernel(
        const float* __restrict__ x,
        const float* __restrict__ W0, const float* __restrict__ b0,
        const float* __restrict__ W1, const float* __restrict__ b1,
        const float* __restrict__ W2, const float* __restrict__ b2,
        const float* __restrict__ W3, const float* __restrict__ b3,
        const float* __restrict__ W4, const float* __restrict__ b4,
        float* __restrict__ out, int nrows) {
    extern __shared__ char lds[];
    char* const bA = lds;            // even half-tiles (rows 0-31 of a tile)
    char* const bB = lds + BUFSZ;    // odd half-tiles (rows 32-63)

    const int lane = threadIdx.x;          // 1 wave per block
    const long long row0 = (long long)blockIdx.x * (NT * 64);
    const char* xbase = reinterpret_cast<const char*>(x + row0 * 64);

    // Per-lane LDS read base: row r0 = lane&31 at r*256 + (r>>2)*48,
    // hA = k-half (lane>>5) selects bytes +32.
    const int r0 = lane & 31;
    const int hA = lane >> 5;
    const int rb = r0 * 256 + (r0 >> 2) * 48 + hA * 32;

    // --- W0^T fragments (A operand), built once, held in registers.
    //     k-step s: A[o = lane&31][k = 16s + 8*hA + j] = W0[k][o].
    const int colB = lane & 31;
    short8 W0h_, W0l_, W1h_, W1l_, W2h_, W2l_, W3h_, W3l_;
    {
        float wf[8];
#define LOADB(s, BH, BL)                                                \
        {                                                               \
            _Pragma("unroll")                                           \
            for (int j = 0; j < 8; ++j)                                 \
                wf[j] = W0[((s) * 16 + 8 * hA + j) * 32 + colB];        \
            BH = mk_hi(wf);                                             \
            BL = mk_lo(wf);                                             \
        }
        LOADB(0, W0h_, W0l_)
        LOADB(1, W1h_, W1l_)
        LOADB(2, W2h_, W2l_)
        LOADB(3, W3h_, W3l_)
#undef LOADB
    }

    // Stage half-tile g (32 rows x 256B, DENSE source) into buf.
    // Call k: 1KB contiguous read at g*8192 + k*1024 + lane*16;
    // dest base k*1072 packs rows 4k..4k+3 with a 48B pad after.
    auto STAGEH = [&](int g, char* buf) {
        const char* s0 = xbase + g * 8192 + lane * 16;
#pragma unroll
        for (int k = 0; k < 8; ++k)
            __builtin_amdgcn_global_load_lds((as1p)(s0 + k * 1024),
                                             (as3p)(buf + k * 1072), 16, 0, 0);
    };

    STAGEH(0, bA);   // prologue: rows 0-31 of tile 0

#pragma unroll 1
    for (int tt = 0; tt < NT; ++tt) {
        f32x16 accA, accB;   // D'[o][col]: accA cols = rows 0-31, accB 32-63
#pragma unroll
        for (int r = 0; r < 16; ++r) { accA[r] = 0.0f; accB[r] = 0.0f; }

// One K=16 step s from buffer CUR into ACC (3-pass split).
#define KSTEP(CUR, s, WH, WL, ACC)                                         \
        {                                                                  \
            float f[8];                                                    \
            const float4 q0 = *reinterpret_cast<const float4*>(            \
                (CUR) + rb + (s) * 64);                                    \
            const float4 q1 = *reinterpret_cast<const float4*>(            \
                (CUR) + rb + (s) * 64 + 16);                               \
            f[0]=q0.x; f[1]=q0.y; f[2]=q0.z; f[3]=q0.w;                    \
            f[4]=q1.x; f[5]=q1.y; f[6]=q1.z; f[7]=q1.w;                    \
            const short8 Xh = mk_hi(f), Xl = mk_lo(f);                     \
            ACC = MFMA(WH, Xh, ACC);                                       \
            ACC = MFMA(WL, Xh, ACC);                                       \
            ACC = MFMA(WH, Xl, ACC);                                       \
        }

        // Phase h=0: stage rows 32-63 (g=2tt+1 -> bB), compute accA from bA.
        {
            STAGEH(2 * tt + 1, bB);
            asm volatile("s_waitcnt vmcnt(8)" ::: "memory");
            __builtin_amdgcn_sched_barrier(0);
            KSTEP(bA, 0, W0h_, W0l_, accA)
            KSTEP(bA, 1, W1h_, W1l_, accA)
            KSTEP(bA, 2, W2h_, W2l_, accA)
            KSTEP(bA, 3, W3h_, W3l_, accA)
        }
        // Phase h=1: stage next tile's rows 0-31 (g=2tt+2 -> bA), compute accB.
        {
            if (tt + 1 < NT) {
                STAGEH(2 * tt + 2, bA);
                asm volatile("s_waitcnt vmcnt(8)" ::: "memory");
            } else {
                asm volatile("s_waitcnt vmcnt(0)" ::: "memory");
            }
            __builtin_amdgcn_sched_barrier(0);
            KSTEP(bB, 0, W0h_, W0l_, accB)
            KSTEP(bB, 1, W1h_, W1l_, accB)
            KSTEP(bB, 2, W2h_, W2l_, accB)
            KSTEP(bB, 3, W3h_, W3l_, accB)
        }
#undef KSTEP

        // --- Align feature halves with permlane32_swap; bias+ReLU in-reg
        //     (R15-proven epilogue, verbatim).
        float xr[32];
#pragma unroll
        for (int reg = 0; reg < 16; ++reg) {
            float a = accA[reg];
            float b = accB[reg];
            asm("v_permlane32_swap_b32 %0, %1" : "+v"(a), "+v"(b));
            const int f0 = (reg & 3) + 8 * (reg >> 2);
            xr[f0]     = fmaxf(a + b0[f0],     0.0f);
            xr[f0 + 4] = fmaxf(b + b0[f0 + 4], 0.0f);
        }

        // Tail layers (next tile's rows-0-31 DMA is in flight during these).
        float h1[12], h2[8], h3[6], h4[2];
        layer<32, 12, true>(W1, b1, xr, h1);
        layer<12, 8, true>(W2, b2, h1, h2);
        layer<8, 6, true>(W3, b3, h2, h3);
        layer<6, 2, false>(W4, b4, h3, h4);

        reinterpret_cast<float2*>(out)[row0 + tt * 64 + lane] =
            make_float2(h4[0], h4[1]);
    }
}

extern "C" void kernel_launch(void* const* d_in, const int* in_sizes, int n_in,
                              void* d_out, int out_size, void* d_ws, size_t ws_size,
                              hipStream_t stream) {
    const float* x  = (const float*)d_in[0];
    const float* W0 = (const float*)d_in[1];
    const float* b0 = (const float*)d_in[2];
    const float* W1 = (const float*)d_in[3];
    const float* b1 = (const float*)d_in[4];
    const float* W2 = (const float*)d_in[5];
    const float* b2 = (const float*)d_in[6];
    const float* W3 = (const float*)d_in[7];
    const float* b3 = (const float*)d_in[8];
    const float* W4 = (const float*)d_in[9];
    const float* b4 = (const float*)d_in[10];
    float* out = (float*)d_out;

    const int nrows = in_sizes[0] / 64;                 // 1,048,576
    const int rows_per_block = NT * 64;                 // 256
    const int grid = nrows / rows_per_block;            // 4096 (exact)
    const size_t shmem = 2 * BUFSZ;                     // 17,152 B

    mlp_kernel<<<grid, BLOCK, shmem, stream>>>(x, W0, b0, W1, b1, W2, b2,
                                               W3, b3, W4, b4, out, nrows);
}

// Round 19
// 55.913 us; speedup vs baseline: 1.2563x; 1.1887x over previous
//
#include <hip/hip_runtime.h>

// 5-layer MLP [B,64]->32->12->8->6->2, fp32 in/out.
// Layer 0 on matrix cores, TRANSPOSED (D' = W0^T x x^T) via
// v_mfma_f32_32x32x16_bf16, 3-pass truncated-bf16 split; feature halves
// aligned with v_permlane32_swap_b32 (R15-proven epilogue, verbatim).
// R19: NO LDS AT ALL. x staged directly into registers with plain
// global_load_dwordx4 (the path fillBuffer/m13 prove reaches ~7 TB/s;
// global_load_lds DMA suspected capped ~4 TB/s). Lane L loads
// x[row=L&31(+32 for accB)][bytes (L>>5)*32 + s*64 + q*16] -- per-phase the
// 8 loads fully consume each row's cachelines within ~20 instrs (L1-safe).
// Two named float4 banks (A*/B*), half-tile (32 rows) prefetch depth 1,
// sched_barrier(0) fences, compiler-counted waitcnts. NT=8, grid=512 ->
// exactly 2 blocks/CU (8 waves/CU), single dispatch round.

typedef __attribute__((ext_vector_type(8))) short short8;
typedef __attribute__((ext_vector_type(16))) float f32x16;
typedef __attribute__((ext_vector_type(4))) unsigned uint4v;

#define BLOCK 256   // 4 independent waves/block
#define NT 8        // 64-row tiles per wave

__device__ __forceinline__ unsigned fbits(float x) {
    return __builtin_bit_cast(unsigned, x);
}
__device__ __forceinline__ float asf(unsigned u) {
    return __builtin_bit_cast(float, u);
}
// (hi16(ub)<<16) | hi16(ua)  -- one v_perm_b32
__device__ __forceinline__ unsigned packhi(unsigned ua, unsigned ub) {
    return __builtin_amdgcn_perm(ub, ua, 0x07060302u);
}
// 8 floats -> 8 truncated bf16 (element j = k-index j)
__device__ __forceinline__ short8 mk_hi(const float* f) {
    uint4v w;
#pragma unroll
    for (int t = 0; t < 4; ++t)
        w[t] = packhi(fbits(f[2 * t]), fbits(f[2 * t + 1]));
    return __builtin_bit_cast(short8, w);
}
// 8 floats -> bf16 of the truncation residuals
__device__ __forceinline__ short8 mk_lo(const float* f) {
    uint4v w;
#pragma unroll
    for (int t = 0; t < 4; ++t) {
        const float la = f[2 * t]     - asf(fbits(f[2 * t])     & 0xFFFF0000u);
        const float lb = f[2 * t + 1] - asf(fbits(f[2 * t + 1]) & 0xFFFF0000u);
        w[t] = packhi(fbits(la), fbits(lb));
    }
    return __builtin_bit_cast(short8, w);
}
#define MFMA(A, B, C) __builtin_amdgcn_mfma_f32_32x32x16_bf16(A, B, C, 0, 0, 0)

template <int IN, int OUT, bool RELU>
__device__ __forceinline__ void layer(const float* __restrict__ W,
                                      const float* __restrict__ b,
                                      const float* h_in, float* h_out) {
#pragma unroll
    for (int o = 0; o < OUT; ++o) h_out[o] = b[o];
#pragma unroll
    for (int i = 0; i < IN; ++i) {
        const float v = h_in[i];
#pragma unroll
        for (int o = 0; o < OUT; ++o)
            h_out[o] = fmaf(v, W[i * OUT + o], h_out[o]);   // uniform -> s_load
    }
    if (RELU) {
#pragma unroll
        for (int o = 0; o < OUT; ++o) h_out[o] = fmaxf(h_out[o], 0.0f);
    }
}

__global__ __launch_bounds__(BLOCK, 2) void mlp_kernel(
        const float* __restrict__ x,
        const float* __restrict__ W0, const float* __restrict__ b0,
        const float* __restrict__ W1, const float* __restrict__ b1,
        const float* __restrict__ W2, const float* __restrict__ b2,
        const float* __restrict__ W3, const float* __restrict__ b3,
        const float* __restrict__ W4, const float* __restrict__ b4,
        float* __restrict__ out, int nrows) {
    const int t = threadIdx.x;
    const int wv = t >> 6;
    const int lane = t & 63;

    const long long row0 = ((long long)blockIdx.x * 4 + wv) * (NT * 64);
    // Per-lane base: row lane&31, k-half (lane>>5)*32 bytes.
    const char* hbase = reinterpret_cast<const char*>(x + row0 * 64) +
                        (lane & 31) * 256 + (lane >> 5) * 32;

    const int hA = lane >> 5;
    const int colB = lane & 31;

    // --- W0^T fragments (A operand), built once, held in registers.
    //     k-step s: A[o = lane&31][k = 16s + 8*hA + j] = W0[k][o].
    short8 W0h_, W0l_, W1h_, W1l_, W2h_, W2l_, W3h_, W3l_;
    {
        float wf[8];
#define LOADW(s, BH, BL)                                                \
        {                                                               \
            _Pragma("unroll")                                           \
            for (int j = 0; j < 8; ++j)                                 \
                wf[j] = W0[((s) * 16 + 8 * hA + j) * 32 + colB];        \
            BH = mk_hi(wf);                                             \
            BL = mk_lo(wf);                                             \
        }
        LOADW(0, W0h_, W0l_)
        LOADW(1, W1h_, W1l_)
        LOADW(2, W2h_, W2l_)
        LOADW(3, W3h_, W3l_)
#undef LOADW
    }

    // Two register banks of 8 float4 (one 32-row half-tile each).
    float4 A0, A1, A2, A3, A4, A5, A6, A7;
    float4 B0, B1, B2, B3, B4, B5, B6, B7;

// Issue the 8 loads of half-tile at byte offset OFF into bank P.
// Offsets within a row: s*64 + q*16, s=0..3, q=0..1.
#define LOADH(OFF, P)                                                      \
    P##0 = *reinterpret_cast<const float4*>(hbase + (OFF) + 0);            \
    P##1 = *reinterpret_cast<const float4*>(hbase + (OFF) + 16);           \
    P##2 = *reinterpret_cast<const float4*>(hbase + (OFF) + 64);           \
    P##3 = *reinterpret_cast<const float4*>(hbase + (OFF) + 80);           \
    P##4 = *reinterpret_cast<const float4*>(hbase + (OFF) + 128);          \
    P##5 = *reinterpret_cast<const float4*>(hbase + (OFF) + 144);          \
    P##6 = *reinterpret_cast<const float4*>(hbase + (OFF) + 192);          \
    P##7 = *reinterpret_cast<const float4*>(hbase + (OFF) + 208);          \
    __builtin_amdgcn_sched_barrier(0);

// One K=16 step from bank registers Q0,Q1 (3-pass bf16 split).
#define KSTEP(Q0, Q1, WH, WL, ACC)                                         \
    {                                                                      \
        float f[8];                                                        \
        f[0] = Q0.x; f[1] = Q0.y; f[2] = Q0.z; f[3] = Q0.w;                \
        f[4] = Q1.x; f[5] = Q1.y; f[6] = Q1.z; f[7] = Q1.w;                \
        const short8 Xh = mk_hi(f), Xl = mk_lo(f);                         \
        ACC = MFMA(WH, Xh, ACC);                                           \
        ACC = MFMA(WL, Xh, ACC);                                           \
        ACC = MFMA(WH, Xl, ACC);                                           \
    }

    // Prologue: half-tile 0 (rows 0-31 of tile 0) into bank A.
    LOADH(0, A)

#pragma unroll 1
    for (int tt = 0; tt < NT; ++tt) {
        const long long toff = (long long)tt * 16384;   // tile byte offset

        f32x16 accA, accB;   // D'[o][col]: accA cols = rows 0-31, accB 32-63
#pragma unroll
        for (int r = 0; r < 16; ++r) { accA[r] = 0.0f; accB[r] = 0.0f; }

        // Phase A: prefetch rows 32-63 of this tile; consume bank A.
        LOADH(toff + 8192, B)
        KSTEP(A0, A1, W0h_, W0l_, accA)
        KSTEP(A2, A3, W1h_, W1l_, accA)
        KSTEP(A4, A5, W2h_, W2l_, accA)
        KSTEP(A6, A7, W3h_, W3l_, accA)

        // Phase B: prefetch rows 0-31 of the NEXT tile; consume bank B.
        if (tt + 1 < NT) {
            LOADH(toff + 16384, A)
        }
        KSTEP(B0, B1, W0h_, W0l_, accB)
        KSTEP(B2, B3, W1h_, W1l_, accB)
        KSTEP(B4, B5, W2h_, W2l_, accB)
        KSTEP(B6, B7, W3h_, W3l_, accB)

        // --- Align feature halves with permlane32_swap; bias+ReLU in-reg
        //     (R15-proven epilogue, verbatim).
        float xr[32];
#pragma unroll
        for (int reg = 0; reg < 16; ++reg) {
            float a = accA[reg];
            float b = accB[reg];
            asm("v_permlane32_swap_b32 %0, %1" : "+v"(a), "+v"(b));
            const int f0 = (reg & 3) + 8 * (reg >> 2);
            xr[f0]     = fmaxf(a + b0[f0],     0.0f);
            xr[f0 + 4] = fmaxf(b + b0[f0 + 4], 0.0f);
        }

        // Tail layers (next tile's half-A loads are in flight during these).
        float h1[12], h2[8], h3[6], h4[2];
        layer<32, 12, true>(W1, b1, xr, h1);
        layer<12, 8, true>(W2, b2, h1, h2);
        layer<8, 6, true>(W3, b3, h2, h3);
        layer<6, 2, false>(W4, b4, h3, h4);

        reinterpret_cast<float2*>(out)[row0 + tt * 64 + lane] =
            make_float2(h4[0], h4[1]);
    }
#undef LOADH
#undef KSTEP
}

extern "C" void kernel_launch(void* const* d_in, const int* in_sizes, int n_in,
                              void* d_out, int out_size, void* d_ws, size_t ws_size,
                              hipStream_t stream) {
    const float* x  = (const float*)d_in[0];
    const float* W0 = (const float*)d_in[1];
    const float* b0 = (const float*)d_in[2];
    const float* W1 = (const float*)d_in[3];
    const float* b1 = (const float*)d_in[4];
    const float* W2 = (const float*)d_in[5];
    const float* b2 = (const float*)d_in[6];
    const float* W3 = (const float*)d_in[7];
    const float* b3 = (const float*)d_in[8];
    const float* W4 = (const float*)d_in[9];
    const float* b4 = (const float*)d_in[10];
    float* out = (float*)d_out;

    const int nrows = in_sizes[0] / 64;                 // 1,048,576
    const int rows_per_block = 4 * NT * 64;             // 2048
    const int grid = nrows / rows_per_block;            // 512 (exact)

    mlp_kernel<<<grid, BLOCK, 0, stream>>>(x, W0, b0, W1, b1, W2, b2,
                                           W3, b3, W4, b4, out, nrows);
}